// Round 1
// baseline (333.287 us; speedup 1.0000x reference)
//
#include <hip/hip_runtime.h>
#include <hip/hip_fp16.h>

#define NFEAT 17
#define HH 8
#define MAXD 13
#define BSZ 256
#define TSZ 512
#define SUMD 59
#define NCH (BSZ*NFEAT)      // 4352 chains
#define NTP (TSZ/2)          // 256 timestep-pairs
#define WSTR 324             // LDS per-feature stride in floats: 16B-aligned, odd # of 16B units

__constant__ int c_dim[NFEAT] = {2,8,12,13,12,1,1,1,1,1,1,1,1,1,1,1,1};
__constant__ int c_off[NFEAT] = {0,2,10,22,35,47,48,49,50,51,52,53,54,55,56,57,58};

// ---------------- Kernel A: gx[b,t,f,g] = sum_d x_pad * W_ih + b_ih, stored fp16 ----------------
// ws layout (fp16): [tp][chain][j][6] = (r,z,n)@t=2tp then (r,z,n)@t=2tp+1, 48 halves = 96B per (tp,chain)
__global__ __launch_bounds__(256) void gates_kernel(
    const float* __restrict__ x, const float* __restrict__ Wih,
    const float* __restrict__ bih, __half* __restrict__ gx) {
  __shared__ float wlds[NFEAT * WSTR];   // [f][d*24+g]
  __shared__ float blds[NFEAT * 24];
  int tid = threadIdx.x;
  for (int i = tid; i < NFEAT * 312; i += 256) {   // 312 = 24*13
    int f = i / 312, r = i - f * 312, g = r / 13, d = r - g * 13;
    wlds[f * WSTR + d * 24 + g] = Wih[i];
  }
  for (int i = tid; i < NFEAT * 24; i += 256) blds[i] = bih[i];
  __syncthreads();

  int id = blockIdx.x * 256 + tid;       // id = tp*NCH + chain (NCH = 17*256, so tp uniform per block)
  int tp = id / NCH;
  int chain = id - tp * NCH;
  int b = chain / NFEAT, f = chain - b * NFEAT;
  int dimf = c_dim[f], off = c_off[f];
  const float* xr = x + ((size_t)b * TSZ + 2 * tp) * SUMD + off;

  float x0[MAXD], x1[MAXD];
  #pragma unroll
  for (int d = 0; d < MAXD; ++d) {
    bool v = d < dimf;                    // W_ih is zero-masked for d>=dimf; zero x to stay in-bounds
    x0[d] = v ? xr[d] : 0.f;
    x1[d] = v ? xr[SUMD + d] : 0.f;
  }
  float a0[24], a1[24];
  #pragma unroll
  for (int g = 0; g < 24; ++g) { float bb = blds[f * 24 + g]; a0[g] = bb; a1[g] = bb; }
  #pragma unroll
  for (int d = 0; d < MAXD; ++d) {
    #pragma unroll
    for (int g = 0; g < 24; ++g) {
      float w = wlds[f * WSTR + d * 24 + g];
      a0[g] += x0[d] * w;
      a1[g] += x1[d] * w;
    }
  }
  union { __half hs[48]; uint4 q[6]; } u;
  #pragma unroll
  for (int j = 0; j < 8; ++j) {
    u.hs[j * 6 + 0] = __float2half(a0[j]);        // r_j, t0
    u.hs[j * 6 + 1] = __float2half(a0[8 + j]);    // z_j, t0
    u.hs[j * 6 + 2] = __float2half(a0[16 + j]);   // n_j, t0
    u.hs[j * 6 + 3] = __float2half(a1[j]);        // r_j, t1
    u.hs[j * 6 + 4] = __float2half(a1[8 + j]);
    u.hs[j * 6 + 5] = __float2half(a1[16 + j]);
  }
  uint4* dst = (uint4*)(gx + (size_t)id * 48);
  #pragma unroll
  for (int q = 0; q < 6; ++q) dst[q] = u.q[q];
}

// ---------------- Kernel B: sequential GRU scan, 8 lanes per chain ----------------
__device__ __forceinline__ float fexp2(float v) { return __builtin_amdgcn_exp2f(v); }
__device__ __forceinline__ float frcp(float v)  { return __builtin_amdgcn_rcpf(v); }
__device__ __forceinline__ float h2f(unsigned s) {
  __half_raw hr; hr.x = (unsigned short)s; return __half2float(__half(hr));
}

__global__ __launch_bounds__(64) void scan_kernel(
    const __half* __restrict__ gx, const float* __restrict__ Whh,
    const float* __restrict__ bhh, float* __restrict__ out) {
  int tid = threadIdx.x;
  int j = tid & 7;                          // hidden unit owned by this lane
  int chain = blockIdx.x * 8 + (tid >> 3);  // 544 blocks * 8 chains = 4352
  int b = chain / NFEAT, f = chain - b * NFEAT;

  const float* wb = Whh + f * 24 * 8;
  float wr[8], wz[8], wn[8];
  #pragma unroll
  for (int k = 0; k < 8; ++k) {
    wr[k] = wb[j * 8 + k];
    wz[k] = wb[(8 + j) * 8 + k];
    wn[k] = wb[(16 + j) * 8 + k];
  }
  float br = bhh[f * 24 + j], bz = bhh[f * 24 + 8 + j], bn = bhh[f * 24 + 16 + j];

  const unsigned* gp = (const unsigned*)gx + (size_t)chain * 24 + j * 3;
  float* op = out + ((size_t)b * TSZ * NFEAT + f) * HH + j;

  float h = 0.f;
  float hk[8];
  #pragma unroll
  for (int k = 0; k < 8; ++k) hk[k] = 0.f;

  const float NL2E = -1.4426950408889634f;    // -log2(e)
  const float N2L2E = -2.885390081777927f;    // -2*log2(e)

  for (int tp = 0; tp < NTP; ++tp) {
    unsigned u0 = gp[0], u1 = gp[1], u2 = gp[2];   // dwordx3: 6 halves = 2 steps
    gp += (size_t)NCH * 24;
    #pragma unroll
    for (int s = 0; s < 2; ++s) {
      float gxr, gxz, gxn;
      if (s == 0) { gxr = h2f(u0 & 0xffff); gxz = h2f(u0 >> 16); gxn = h2f(u1 & 0xffff); }
      else        { gxr = h2f(u1 >> 16);    gxz = h2f(u2 & 0xffff); gxn = h2f(u2 >> 16); }
      float ghr = br, ghz = bz, ghn = bn;
      #pragma unroll
      for (int k = 0; k < 8; ++k) {
        ghr += hk[k] * wr[k];
        ghz += hk[k] * wz[k];
        ghn += hk[k] * wn[k];
      }
      float r = frcp(1.f + fexp2((gxr + ghr) * NL2E));
      float z = frcp(1.f + fexp2((gxz + ghz) * NL2E));
      float e = fexp2((gxn + r * ghn) * N2L2E);
      float n = (1.f - e) * frcp(1.f + e);          // tanh
      h = n + z * (h - n);
      *op = h;
      op += NFEAT * HH;
      #pragma unroll
      for (int k = 0; k < 8; ++k) hk[k] = __shfl(h, k, 8);
    }
  }
}

extern "C" void kernel_launch(void* const* d_in, const int* in_sizes, int n_in,
                              void* d_out, int out_size, void* d_ws, size_t ws_size,
                              hipStream_t stream) {
  const float* x   = (const float*)d_in[0];
  const float* Wih = (const float*)d_in[1];
  const float* Whh = (const float*)d_in[2];
  const float* bih = (const float*)d_in[3];
  const float* bhh = (const float*)d_in[4];
  float* out = (float*)d_out;
  __half* gxws = (__half*)d_ws;   // needs NTP*NCH*96 B = ~107 MB

  hipLaunchKernelGGL(gates_kernel, dim3(NTP * NCH / 256), dim3(256), 0, stream,
                     x, Wih, bih, gxws);
  hipLaunchKernelGGL(scan_kernel, dim3(NCH / 8), dim3(64), 0, stream,
                     gxws, Whh, bhh, out);
}

// Round 2
// 235.012 us; speedup vs baseline: 1.4182x; 1.4182x over previous
//
#include <hip/hip_runtime.h>
#include <hip/hip_fp16.h>

#define NFEAT 17
#define HH 8
#define MAXD 13
#define BSZ 256
#define TSZ 512
#define SUMD 59
#define NCH (BSZ*NFEAT)      // 4352 chains
#define NTP (TSZ/2)          // 256 timestep-pairs

__constant__ int c_dim[NFEAT] = {2,8,12,13,12,1,1,1,1,1,1,1,1,1,1,1,1};
__constant__ int c_off[NFEAT] = {0,2,10,22,35,47,48,49,50,51,52,53,54,55,56,57,58};

// ---------- Kernel T: transpose W_ih [f][g][d] -> wT [f][d][g] (g contiguous, s_load friendly) ----------
__global__ __launch_bounds__(256) void transpose_wih(const float* __restrict__ Wih,
                                                     float* __restrict__ wT) {
  int i = blockIdx.x * 256 + threadIdx.x;
  if (i < NFEAT * 312) {
    int f = i / 312, r = i - f * 312, d = r / 24, g = r - d * 24;
    wT[i] = Wih[f * 312 + g * 13 + d];
  }
}

// ---------- Kernel A: gx = x_pad . W_ih^T + b_ih, fp16, chain-major [chain][tp][j][6] ----------
template<int D>
__device__ __forceinline__ void feat_accum(const float* __restrict__ xr,
                                           const float* __restrict__ wf,
                                           const float* __restrict__ bf,
                                           float* a0, float* a1) {
  float x0[D], x1[D];
  #pragma unroll
  for (int d = 0; d < D; ++d) { x0[d] = xr[d]; x1[d] = xr[SUMD + d]; }
  #pragma unroll
  for (int g = 0; g < 24; ++g) { float bb = bf[g]; a0[g] = bb; a1[g] = bb; }
  #pragma unroll
  for (int d = 0; d < D; ++d) {
    #pragma unroll
    for (int g = 0; g < 24; ++g) {
      float w = wf[d * 24 + g];          // wave-uniform -> scalar load
      a0[g] = fmaf(x0[d], w, a0[g]);
      a1[g] = fmaf(x1[d], w, a1[g]);
    }
  }
}

__global__ __launch_bounds__(256) void gates_kernel(const float* __restrict__ x,
                                                    const float* __restrict__ wT,
                                                    const float* __restrict__ bih,
                                                    __half* __restrict__ gx) {
  int tp = threadIdx.x;                  // 0..255 timestep-pair
  int b = blockIdx.x;                    // 0..255 batch
  const float* xrow = x + ((size_t)b * TSZ + 2 * tp) * SUMD;
  #pragma unroll 1
  for (int f = 0; f < NFEAT; ++f) {
    int D = c_dim[f], off = c_off[f];
    const float* wf = wT + f * 312;      // uniform per wave
    const float* bf = bih + f * 24;
    const float* xr = xrow + off;
    float a0[24], a1[24];
    switch (D) {
      case 13: feat_accum<13>(xr, wf, bf, a0, a1); break;
      case 12: feat_accum<12>(xr, wf, bf, a0, a1); break;
      case 8:  feat_accum<8>(xr, wf, bf, a0, a1); break;
      case 2:  feat_accum<2>(xr, wf, bf, a0, a1); break;
      default: feat_accum<1>(xr, wf, bf, a0, a1); break;
    }
    union { __half hs[48]; uint4 q[6]; } u;
    #pragma unroll
    for (int j = 0; j < 8; ++j) {
      u.hs[j * 6 + 0] = __float2half(a0[j]);        // r_j, t0
      u.hs[j * 6 + 1] = __float2half(a0[8 + j]);    // z_j, t0
      u.hs[j * 6 + 2] = __float2half(a0[16 + j]);   // n_j, t0
      u.hs[j * 6 + 3] = __float2half(a1[j]);        // r_j, t1
      u.hs[j * 6 + 4] = __float2half(a1[8 + j]);
      u.hs[j * 6 + 5] = __float2half(a1[16 + j]);
    }
    size_t chain = (size_t)b * NFEAT + f;
    uint4* dst = (uint4*)(gx + (chain * NTP + (size_t)tp) * 48);
    #pragma unroll
    for (int q = 0; q < 6; ++q) dst[q] = u.q[q];    // 96B contiguous per lane
  }
}

// ---------- Kernel B: sequential GRU scan, 8 lanes/chain, 4-deep prefetch ----------
__device__ __forceinline__ float fexp2(float v) { return __builtin_amdgcn_exp2f(v); }
__device__ __forceinline__ float frcp(float v)  { return __builtin_amdgcn_rcpf(v); }
__device__ __forceinline__ float h2f(unsigned s) {
  __half_raw hr; hr.x = (unsigned short)s; return __half2float(__half(hr));
}
__device__ __forceinline__ uint3 ldu3(const unsigned* __restrict__ p) {
  uint3 v; v.x = p[0]; v.y = p[1]; v.z = p[2]; return v;
}

__global__ __launch_bounds__(64) void scan_kernel(const __half* __restrict__ gx,
                                                  const float* __restrict__ Whh,
                                                  const float* __restrict__ bhh,
                                                  float* __restrict__ out) {
  int tid = threadIdx.x;
  int j = tid & 7;                          // hidden unit owned by this lane
  int chain = blockIdx.x * 8 + (tid >> 3);
  int b = chain / NFEAT, f = chain - b * NFEAT;

  const float* wb = Whh + f * 192;
  float wr[8], wz[8], wn[8];
  #pragma unroll
  for (int k = 0; k < 8; ++k) {
    wr[k] = wb[j * 8 + k];
    wz[k] = wb[64 + j * 8 + k];
    wn[k] = wb[128 + j * 8 + k];
  }
  float br = bhh[f * 24 + j], bz = bhh[f * 24 + 8 + j], bn = bhh[f * 24 + 16 + j];

  const unsigned* gp = (const unsigned*)gx + (size_t)chain * (NTP * 24) + j * 3;
  float* op = out + ((size_t)b * TSZ * NFEAT + f) * HH + j;

  float h = 0.f;
  float hk0 = 0.f, hk1 = 0.f, hk2 = 0.f, hk3 = 0.f, hk4 = 0.f, hk5 = 0.f, hk6 = 0.f, hk7 = 0.f;

  const float NL2E = -1.4426950408889634f;    // -log2(e)
  const float N2L2E = -2.885390081777927f;    // -2*log2(e)

  // broadcast h of lane (group_base | k) within 8-lane group, static swizzle
  #define SW(k) __int_as_float(__builtin_amdgcn_ds_swizzle(__float_as_int(h), ((k) << 5) | 0x18))

  #define SSTEP(GXR, GXZ, GXN) do {                                                   \
    float pr = (fmaf(hk0, wr[0], hk1 * wr[1]) + fmaf(hk2, wr[2], hk3 * wr[3]))        \
             + (fmaf(hk4, wr[4], hk5 * wr[5]) + fmaf(hk6, wr[6], hk7 * wr[7]));       \
    float pz = (fmaf(hk0, wz[0], hk1 * wz[1]) + fmaf(hk2, wz[2], hk3 * wz[3]))        \
             + (fmaf(hk4, wz[4], hk5 * wz[5]) + fmaf(hk6, wz[6], hk7 * wz[7]));       \
    float pn = (fmaf(hk0, wn[0], hk1 * wn[1]) + fmaf(hk2, wn[2], hk3 * wn[3]))        \
             + (fmaf(hk4, wn[4], hk5 * wn[5]) + fmaf(hk6, wn[6], hk7 * wn[7]));       \
    float r = frcp(1.f + fexp2(((GXR) + br + pr) * NL2E));                            \
    float z = frcp(1.f + fexp2(((GXZ) + bz + pz) * NL2E));                            \
    float e = fexp2(((GXN) + r * (bn + pn)) * N2L2E);                                 \
    float n = (1.f - e) * frcp(1.f + e);                                              \
    h = fmaf(z, h - n, n);                                                            \
    *op = h; op += NFEAT * HH;                                                        \
    hk0 = SW(0); hk1 = SW(1); hk2 = SW(2); hk3 = SW(3);                               \
    hk4 = SW(4); hk5 = SW(5); hk6 = SW(6); hk7 = SW(7);                               \
  } while (0)

  #define PROC(U) do {                                                                \
    SSTEP(h2f(U.x & 0xffff), h2f(U.x >> 16), h2f(U.y & 0xffff));                      \
    SSTEP(h2f(U.y >> 16), h2f(U.z & 0xffff), h2f(U.z >> 16));                         \
  } while (0)

  uint3 A = ldu3(gp), B = ldu3(gp + 24), C = ldu3(gp + 48), Dv = ldu3(gp + 72);
  for (int tp = 0; tp < NTP; tp += 4) {
    PROC(A); { int t = tp + 4; t = t < NTP ? t : NTP - 1; A  = ldu3(gp + (size_t)t * 24); }
    PROC(B); { int t = tp + 5; t = t < NTP ? t : NTP - 1; B  = ldu3(gp + (size_t)t * 24); }
    PROC(C); { int t = tp + 6; t = t < NTP ? t : NTP - 1; C  = ldu3(gp + (size_t)t * 24); }
    PROC(Dv);{ int t = tp + 7; t = t < NTP ? t : NTP - 1; Dv = ldu3(gp + (size_t)t * 24); }
  }
  #undef SW
  #undef SSTEP
  #undef PROC
}

extern "C" void kernel_launch(void* const* d_in, const int* in_sizes, int n_in,
                              void* d_out, int out_size, void* d_ws, size_t ws_size,
                              hipStream_t stream) {
  const float* x   = (const float*)d_in[0];
  const float* Wih = (const float*)d_in[1];
  const float* Whh = (const float*)d_in[2];
  const float* bih = (const float*)d_in[3];
  const float* bhh = (const float*)d_in[4];
  float* out = (float*)d_out;
  __half* gxws = (__half*)d_ws;            // NCH*NTP*96 B ~= 107 MB (fit proven in round 1)

  // W_ih transpose scratch lives in the tail of d_out; gates reads it before
  // scan overwrites every element of d_out (stream-ordered kernels).
  float* wT = out + ((size_t)out_size - NFEAT * 312);

  hipLaunchKernelGGL(transpose_wih, dim3(21), dim3(256), 0, stream, Wih, wT);
  hipLaunchKernelGGL(gates_kernel, dim3(BSZ), dim3(256), 0, stream, x, wT, bih, gxws);
  hipLaunchKernelGGL(scan_kernel, dim3(NCH / 8), dim3(64), 0, stream, gxws, Whh, bhh, out);
}